// Round 5
// baseline (152.140 us; speedup 1.0000x reference)
//
#include <hip/hip_runtime.h>
#include <stdint.h>

// Problem constants: B=2, S=2048, E=1024, H=16, D=64, M = B*S = 4096
#define LOG2E 1.4426950408889634f
#define QSCALE (0.125f * LOG2E)   // fold 1/sqrt(64) and log2(e): softmax in exp2 domain

using u16 = unsigned short;
using u32 = unsigned int;

typedef __attribute__((ext_vector_type(8))) short short8;
typedef __attribute__((ext_vector_type(4))) float f32x4;
typedef __attribute__((ext_vector_type(16))) float f32x16;

__device__ __forceinline__ u16 f32_bf16(float f) {
  union { float f; u32 u; } v; v.f = f;
  u32 u = v.u;
  u += 0x7FFF + ((u >> 16) & 1);   // RNE
  return (u16)(u >> 16);
}

__device__ __forceinline__ float max3f(float a, float b, float c) {
  return fmaxf(fmaxf(a, b), c);    // clang fuses to v_max3_f32
}

__device__ __forceinline__ void gload_lds16(const void* g, void* l) {
  __builtin_amdgcn_global_load_lds(
      (const __attribute__((address_space(1))) u32*)(uintptr_t)g,
      (__attribute__((address_space(3))) u32*)(u32)(uintptr_t)l, 16, 0, 0);
}

// ---------------- pre-passes ----------------

__global__ __launch_bounds__(256) void cvt_f32_bf16(const float* __restrict__ in,
                                                    u16* __restrict__ out, int n4) {
  for (int i = blockIdx.x * blockDim.x + threadIdx.x; i < n4;
       i += gridDim.x * blockDim.x) {
    float4 v = ((const float4*)in)[i];
    union { u16 h[4]; uint2 u; } o;
    o.h[0] = f32_bf16(v.x); o.h[1] = f32_bf16(v.y);
    o.h[2] = f32_bf16(v.z); o.h[3] = f32_bf16(v.w);
    ((uint2*)out)[i] = o.u;
  }
}

// out[n][k] = bf16(in[k][n]);  in is [K][N] fp32 row-major
__global__ __launch_bounds__(256) void transpose_bf16(const float* __restrict__ in,
                                                      u16* __restrict__ out,
                                                      int K, int N) {
  __shared__ float t[32][33];
  const int n0 = blockIdx.x * 32, k0 = blockIdx.y * 32;
  const int tx = threadIdx.x, ty = threadIdx.y;
#pragma unroll
  for (int j = 0; j < 32; j += 8)
    t[ty + j][tx] = in[(size_t)(k0 + ty + j) * N + n0 + tx];
  __syncthreads();
#pragma unroll
  for (int j = 0; j < 32; j += 8)
    out[(size_t)(n0 + ty + j) * K + k0 + tx] = f32_bf16(t[tx][ty + j]);
}

// ---------------- GEMM: C = A[M,K] * Bt[N,K]^T + bias ----------------
// 128x128 tile, 4 waves (2x2), BK=32, global_load_lds staging (m97 structure).
// MODE 0: QKV epilogue -> scatter to Q[B,H,S,D]*QSCALE, K[B,H,S,D], Vt[B,H,D,S] (bf16)
// MODE 1: fp32 out + bias to fout[M,1024]
template <int MODE>
__global__ __launch_bounds__(256) void gemm_bt(
    const u16* __restrict__ A, const u16* __restrict__ Bt,
    const float* __restrict__ bias,
    u16* __restrict__ qb, u16* __restrict__ kb, u16* __restrict__ vtb,
    float* __restrict__ fout) {
  __shared__ u16 lA[128 * 32];
  __shared__ u16 lB[128 * 32];
  const int tid = threadIdx.x;
  const int w = tid >> 6, l = tid & 63;
  const int bm = blockIdx.y, bn = blockIdx.x;
  const size_t m0 = (size_t)bm * 128, n0 = (size_t)bn * 128;
  const int wr = w >> 1, wc = w & 1;

  f32x4 acc[4][4] = {};

  const int arow = w * 16 + (l >> 2);
  const int acol = (l & 3) * 8;
  const u16* gA = A + (m0 + arow) * 1024 + acol;
  const u16* gB = Bt + (n0 + arow) * 1024 + acol;
  u16* lAw = lA + w * 512;  // HW adds lane*16B
  u16* lBw = lB + w * 512;

  for (int k0 = 0; k0 < 1024; k0 += 32) {
    gload_lds16(gA + k0, lAw);
    gload_lds16(gA + k0 + 64 * 1024, lAw + 2048);
    gload_lds16(gB + k0, lBw);
    gload_lds16(gB + k0 + 64 * 1024, lBw + 2048);
    __syncthreads();
    short8 af[4], bf[4];
#pragma unroll
    for (int m = 0; m < 4; ++m)
      af[m] = *(const short8*)&lA[(wr * 64 + m * 16 + (l & 15)) * 32 + (l >> 4) * 8];
#pragma unroll
    for (int n = 0; n < 4; ++n)
      bf[n] = *(const short8*)&lB[(wc * 64 + n * 16 + (l & 15)) * 32 + (l >> 4) * 8];
#pragma unroll
    for (int m = 0; m < 4; ++m)
#pragma unroll
      for (int n = 0; n < 4; ++n)
        acc[m][n] = __builtin_amdgcn_mfma_f32_16x16x32_bf16(af[m], bf[n], acc[m][n], 0, 0, 0);
    __syncthreads();
  }

  if (MODE == 0) {
#pragma unroll
    for (int m = 0; m < 4; ++m) {
      const int row = (int)m0 + wr * 64 + m * 16 + ((l >> 4) << 2);
      const int b = row >> 11, s = row & 2047;
#pragma unroll
      for (int n = 0; n < 4; ++n) {
        const int col = (int)n0 + wc * 64 + n * 16 + (l & 15);
        const int part = col >> 10;
        const int h = (col & 1023) >> 6, d = col & 63;
        const float bv = bias[col];
        const size_t bh = (size_t)(b * 16 + h);
#pragma unroll
        for (int r = 0; r < 4; ++r) {
          const float v = acc[m][n][r] + bv;
          const int ss = s + r;
          if (part == 0)
            qb[(bh * 2048 + ss) * 64 + d] = f32_bf16(v * QSCALE);
          else if (part == 1)
            kb[(bh * 2048 + ss) * 64 + d] = f32_bf16(v);
          else
            vtb[(bh * 64 + d) * 2048 + ss] = f32_bf16(v);  // V transposed
        }
      }
    }
  } else {
#pragma unroll
    for (int m = 0; m < 4; ++m) {
      const size_t row = m0 + wr * 64 + m * 16 + ((l >> 4) << 2);
#pragma unroll
      for (int n = 0; n < 4; ++n) {
        const size_t col = n0 + wc * 64 + n * 16 + (l & 15);
        const float bv = bias[col];
#pragma unroll
        for (int r = 0; r < 4; ++r)
          fout[(row + r) * 1024 + col] = acc[m][n][r] + bv;
      }
    }
  }
}

// ---------------- causal flash attention, swapped-operand, kv-split-4 ----------------
// 2048 blocks x 256 threads; block = (bh, q-tile of 32 rows). Wave w owns kv PAIRS
// p == w (mod 4); pair p covers contiguous kv tiles {2p, 2p+1} (64 kv per body).
// Rolling pointers + 1-pair-ahead K prefetch; mask-free main loop, peeled diagonal.
// Waves 1..3 deposit unnormalized partial O^T/m/l in LDS; wave 0 merges and stores.
__global__ __launch_bounds__(256) void attn_fwd5(const u16* __restrict__ Qb,
                                                 const u16* __restrict__ Kb,
                                                 const u16* __restrict__ Vt,
                                                 u16* __restrict__ AO) {
  __shared__ float o_lds[3][8][64][4];   // [wave-1][r8][lane][e] partial O^T
  __shared__ float lm_lds[3][2][64];     // [wave-1][{m,l}][lane]
  const int l = threadIdx.x & 63, w = threadIdx.x >> 6;
  const int bid = blockIdx.x;
  const int xcd = bid & 7, idx = bid >> 3;
  const int bh = xcd * 4 + (idx & 3);
  const int j = 63 - (idx >> 2);       // q-tile index, 0..63 (heavy first)
  const int lq = l & 31, hi = l >> 5;
  const int q = j * 32 + lq;           // q row within S

  const u16* Qh = Qb + (size_t)bh * 131072;
  const u16* Kh = Kb + (size_t)bh * 131072;
  const u16* Vh = Vt + (size_t)bh * 131072;

  // Q B-fragments (col=q=lane&31, k=d), 4 mfmas cover D=64
  short8 qf[4];
#pragma unroll
  for (int kk = 0; kk < 4; ++kk)
    qf[kk] = *(const short8*)&Qh[(size_t)q * 64 + kk * 16 + hi * 8];

  f32x16 oA = {}, oB = {};             // O^T cols: d 0..31 / 32..63
  float m = -3.0e38f, lsum = 0.f;

  const int P = j >> 1;                // diagonal pair index
  const bool owner = (P & 3) == w;

  if (P >= w) {
    const u16* pK = Kh + lq * 64 + hi * 8 + (size_t)(2 * w) * 2048;
    const u16* pV = Vh + (size_t)lq * 2048 + hi * 8 + 2 * w * 32;
    short8 kf[8];                      // K fragments for current pair (2 tiles)
#pragma unroll
    for (int t = 0; t < 8; ++t)
      kf[t] = *(const short8*)&pK[(t >> 2) * 2048 + (t & 3) * 16];

    const int nfull = owner ? ((P - w) >> 2) : (((P - w) >> 2) + 1);

    // process one 64-kv pair; mask2: causal-mask second tile; pref: prefetch next pair K
    auto process2 = [&](const u16* pVt, bool mask2, bool pref) {
      short8 vf[8];
#pragma unroll
      for (int dh = 0; dh < 2; ++dh)
#pragma unroll
        for (int ks = 0; ks < 4; ++ks)
          vf[dh * 4 + ks] = *(const short8*)&pVt[dh * 65536 + ks * 16];

      f32x16 st0 = {}, st1 = {};
      __builtin_amdgcn_s_setprio(1);
#pragma unroll
      for (int kk = 0; kk < 4; ++kk)
        st0 = __builtin_amdgcn_mfma_f32_32x32x16_bf16(kf[kk], qf[kk], st0, 0, 0, 0);
#pragma unroll
      for (int kk = 0; kk < 4; ++kk)
        st1 = __builtin_amdgcn_mfma_f32_32x32x16_bf16(kf[4 + kk], qf[kk], st1, 0, 0, 0);
      __builtin_amdgcn_s_setprio(0);

      if (pref) {
        pK += 16384;                   // next pair for this wave (+8 tiles)
#pragma unroll
        for (int t = 0; t < 8; ++t)
          kf[t] = *(const short8*)&pK[(t >> 2) * 2048 + (t & 3) * 16];
      }
      if (mask2) {
        const int qm = lq - hi * 4;
#pragma unroll
        for (int r = 0; r < 16; ++r) {
          const int t = (r & 3) + 8 * (r >> 2);
          if (t > qm) st1[r] = -3.0e38f;
        }
      }

      // row max over 64 kv (v_max3 tree) + cross-half exchange
      float a0 = max3f(st0[0], st0[1], st0[2]);
      float a1 = max3f(st0[3], st0[4], st0[5]);
      float a2 = max3f(st0[6], st0[7], st0[8]);
      float a3 = max3f(st0[9], st0[10], st0[11]);
      float a4 = max3f(st0[12], st0[13], st0[14]);
      float a5 = max3f(st0[15], st1[0], st1[1]);
      float a6 = max3f(st1[2], st1[3], st1[4]);
      float a7 = max3f(st1[5], st1[6], st1[7]);
      float a8 = max3f(st1[8], st1[9], st1[10]);
      float a9 = max3f(st1[11], st1[12], st1[13]);
      float a10 = fmaxf(st1[14], st1[15]);
      float b0 = max3f(a0, a1, a2);
      float b1 = max3f(a3, a4, a5);
      float b2 = max3f(a6, a7, a8);
      float b3 = max3f(a9, a10, b0);
      float pm = max3f(b1, b2, b3);
      pm = fmaxf(pm, __shfl_xor(pm, 32));

      // defer-max (T13): skip O rescale while max growth <= 8 (exp2 domain)
      if (!__all(pm <= m + 8.0f)) {
        const float mn = fmaxf(m, pm);
        const float alpha = __builtin_amdgcn_exp2f(m - mn);
        lsum *= alpha;
#pragma unroll
        for (int r = 0; r < 16; ++r) { oA[r] *= alpha; oB[r] *= alpha; }
        m = mn;
      }

#pragma unroll
      for (int r = 0; r < 16; ++r) st0[r] = __builtin_amdgcn_exp2f(st0[r] - m);
#pragma unroll
      for (int r = 0; r < 16; ++r) st1[r] = __builtin_amdgcn_exp2f(st1[r] - m);

      float s0 = (st0[0] + st0[1]) + (st0[2] + st0[3]);
      float s1 = (st0[4] + st0[5]) + (st0[6] + st0[7]);
      float s2 = (st0[8] + st0[9]) + (st0[10] + st0[11]);
      float s3 = (st0[12] + st0[13]) + (st0[14] + st0[15]);
      float s4 = (st1[0] + st1[1]) + (st1[2] + st1[3]);
      float s5 = (st1[4] + st1[5]) + (st1[6] + st1[7]);
      float s6 = (st1[8] + st1[9]) + (st1[10] + st1[11]);
      float s7 = (st1[12] + st1[13]) + (st1[14] + st1[15]);
      float rs = ((s0 + s1) + (s2 + s3)) + ((s4 + s5) + (s6 + s7));
      rs += __shfl_xor(rs, 32);
      lsum += rs;

      // pack tile0 -> pf0,pf1
      union { u32 u[4]; short8 s; } pf0, pf1, pf2, pf3;
      {
        u32 pk[8];
#pragma unroll
        for (int t2 = 0; t2 < 8; ++t2)
          asm("v_cvt_pk_bf16_f32 %0, %1, %2" : "=v"(pk[t2]) : "v"(st0[2 * t2]), "v"(st0[2 * t2 + 1]));
        u32 a0_ = pk[0], a1_ = pk[2]; asm("v_permlane32_swap_b32 %0, %1" : "+v"(a0_), "+v"(a1_));
        u32 a2_ = pk[1], a3_ = pk[3]; asm("v_permlane32_swap_b32 %0, %1" : "+v"(a2_), "+v"(a3_));
        u32 c0_ = pk[4], c1_ = pk[6]; asm("v_permlane32_swap_b32 %0, %1" : "+v"(c0_), "+v"(c1_));
        u32 c2_ = pk[5], c3_ = pk[7]; asm("v_permlane32_swap_b32 %0, %1" : "+v"(c2_), "+v"(c3_));
        pf0.u[0] = a0_; pf0.u[1] = a2_; pf0.u[2] = a1_; pf0.u[3] = a3_;
        pf1.u[0] = c0_; pf1.u[1] = c2_; pf1.u[2] = c1_; pf1.u[3] = c3_;
      }
      // pack tile1 -> pf2,pf3
      {
        u32 pk[8];
#pragma unroll
        for (int t2 = 0; t2 < 8; ++t2)
          asm("v_cvt_pk_bf16_f32 %0, %1, %2" : "=v"(pk[t2]) : "v"(st1[2 * t2]), "v"(st1[2 * t2 + 1]));
        u32 a0_ = pk[0], a1_ = pk[2]; asm("v_permlane32_swap_b32 %0, %1" : "+v"(a0_), "+v"(a1_));
        u32 a2_ = pk[1], a3_ = pk[3]; asm("v_permlane32_swap_b32 %0, %1" : "+v"(a2_), "+v"(a3_));
        u32 c0_ = pk[4], c1_ = pk[6]; asm("v_permlane32_swap_b32 %0, %1" : "+v"(c0_), "+v"(c1_));
        u32 c2_ = pk[5], c3_ = pk[7]; asm("v_permlane32_swap_b32 %0, %1" : "+v"(c2_), "+v"(c3_));
        pf2.u[0] = a0_; pf2.u[1] = a2_; pf2.u[2] = a1_; pf2.u[3] = a3_;
        pf3.u[0] = c0_; pf3.u[1] = c2_; pf3.u[2] = c1_; pf3.u[3] = c3_;
      }

      // O^T += V^T * P^T  (8 mfma)
      __builtin_amdgcn_s_setprio(1);
      oA = __builtin_amdgcn_mfma_f32_32x32x16_bf16(vf[0], pf0.s, oA, 0, 0, 0);
      oA = __builtin_amdgcn_mfma_f32_32x32x16_bf16(vf[1], pf1.s, oA, 0, 0, 0);
      oA = __builtin_amdgcn_mfma_f32_32x32x16_bf16(vf[2], pf2.s, oA, 0, 0, 0);
      oA = __builtin_amdgcn_mfma_f32_32x32x16_bf16(vf[3], pf3.s, oA, 0, 0, 0);
      oB = __builtin_amdgcn_mfma_f32_32x32x16_bf16(vf[4], pf0.s, oB, 0, 0, 0);
      oB = __builtin_amdgcn_mfma_f32_32x32x16_bf16(vf[5], pf1.s, oB, 0, 0, 0);
      oB = __builtin_amdgcn_mfma_f32_32x32x16_bf16(vf[6], pf2.s, oB, 0, 0, 0);
      oB = __builtin_amdgcn_mfma_f32_32x32x16_bf16(vf[7], pf3.s, oB, 0, 0, 0);
      __builtin_amdgcn_s_setprio(0);
    };

    // final masked SINGLE tile (j even): tile 2P == j
    auto process1m = [&](const u16* pVt) {
      short8 vf[4];
      vf[0] = *(const short8*)&pVt[0];
      vf[1] = *(const short8*)&pVt[16];
      vf[2] = *(const short8*)&pVt[65536];
      vf[3] = *(const short8*)&pVt[65536 + 16];
      f32x16 st0 = {};
      __builtin_amdgcn_s_setprio(1);
#pragma unroll
      for (int kk = 0; kk < 4; ++kk)
        st0 = __builtin_amdgcn_mfma_f32_32x32x16_bf16(kf[kk], qf[kk], st0, 0, 0, 0);
      __builtin_amdgcn_s_setprio(0);
      const int qm = lq - hi * 4;
#pragma unroll
      for (int r = 0; r < 16; ++r) {
        const int t = (r & 3) + 8 * (r >> 2);
        if (t > qm) st0[r] = -3.0e38f;
      }
      float a0 = max3f(st0[0], st0[1], st0[2]);
      float a1 = max3f(st0[3], st0[4], st0[5]);
      float a2 = max3f(st0[6], st0[7], st0[8]);
      float a3 = max3f(st0[9], st0[10], st0[11]);
      float a4 = max3f(st0[12], st0[13], st0[14]);
      float b0 = max3f(a0, a1, a2);
      float b1 = max3f(a3, a4, st0[15]);
      float pm = fmaxf(b0, b1);
      pm = fmaxf(pm, __shfl_xor(pm, 32));
      if (!__all(pm <= m + 8.0f)) {
        const float mn = fmaxf(m, pm);
        const float alpha = __builtin_amdgcn_exp2f(m - mn);
        lsum *= alpha;
#pragma unroll
        for (int r = 0; r < 16; ++r) { oA[r] *= alpha; oB[r] *= alpha; }
        m = mn;
      }
#pragma unroll
      for (int r = 0; r < 16; ++r) st0[r] = __builtin_amdgcn_exp2f(st0[r] - m);
      float s0 = (st0[0] + st0[1]) + (st0[2] + st0[3]);
      float s1 = (st0[4] + st0[5]) + (st0[6] + st0[7]);
      float s2 = (st0[8] + st0[9]) + (st0[10] + st0[11]);
      float s3 = (st0[12] + st0[13]) + (st0[14] + st0[15]);
      float rs = (s0 + s1) + (s2 + s3);
      rs += __shfl_xor(rs, 32);
      lsum += rs;
      union { u32 u[4]; short8 s; } pf0, pf1;
      u32 pk[8];
#pragma unroll
      for (int t2 = 0; t2 < 8; ++t2)
        asm("v_cvt_pk_bf16_f32 %0, %1, %2" : "=v"(pk[t2]) : "v"(st0[2 * t2]), "v"(st0[2 * t2 + 1]));
      u32 a0_ = pk[0], a1_ = pk[2]; asm("v_permlane32_swap_b32 %0, %1" : "+v"(a0_), "+v"(a1_));
      u32 a2_ = pk[1], a3_ = pk[3]; asm("v_permlane32_swap_b32 %0, %1" : "+v"(a2_), "+v"(a3_));
      u32 c0_ = pk[4], c1_ = pk[6]; asm("v_permlane32_swap_b32 %0, %1" : "+v"(c0_), "+v"(c1_));
      u32 c2_ = pk[5], c3_ = pk[7]; asm("v_permlane32_swap_b32 %0, %1" : "+v"(c2_), "+v"(c3_));
      pf0.u[0] = a0_; pf0.u[1] = a2_; pf0.u[2] = a1_; pf0.u[3] = a3_;
      pf1.u[0] = c0_; pf1.u[1] = c2_; pf1.u[2] = c1_; pf1.u[3] = c3_;
      __builtin_amdgcn_s_setprio(1);
      oA = __builtin_amdgcn_mfma_f32_32x32x16_bf16(vf[0], pf0.s, oA, 0, 0, 0);
      oA = __builtin_amdgcn_mfma_f32_32x32x16_bf16(vf[1], pf1.s, oA, 0, 0, 0);
      oB = __builtin_amdgcn_mfma_f32_32x32x16_bf16(vf[2], pf0.s, oB, 0, 0, 0);
      oB = __builtin_amdgcn_mfma_f32_32x32x16_bf16(vf[3], pf1.s, oB, 0, 0, 0);
      __builtin_amdgcn_s_setprio(0);
    };

    const u16* pVloc = pV;
    for (int i = 0; i < nfull; ++i) {
      process2(pVloc, false, true);
      pVloc += 256;                    // +4 pairs = +256 kv
    }
    if (owner) {
      if (j & 1) process2(pVloc, true, false);
      else       process1m(pVloc);
    }
  }

  // merge wave partials via LDS (waves 1..3 deposit; wave 0 merges)
  if (w > 0) {
#pragma unroll
    for (int r4 = 0; r4 < 4; ++r4) {
      f32x4 a = { oA[4 * r4], oA[4 * r4 + 1], oA[4 * r4 + 2], oA[4 * r4 + 3] };
      f32x4 b = { oB[4 * r4], oB[4 * r4 + 1], oB[4 * r4 + 2], oB[4 * r4 + 3] };
      *(f32x4*)&o_lds[w - 1][r4][l][0] = a;
      *(f32x4*)&o_lds[w - 1][r4 + 4][l][0] = b;
    }
    lm_lds[w - 1][0][l] = m;
    lm_lds[w - 1][1][l] = lsum;
  }
  __syncthreads();
  if (w == 0) {
    const float m1 = lm_lds[0][0][l], l1 = lm_lds[0][1][l];
    const float m2 = lm_lds[1][0][l], l2 = lm_lds[1][1][l];
    const float m3 = lm_lds[2][0][l], l3 = lm_lds[2][1][l];
    const float M = fmaxf(fmaxf(m, m1), fmaxf(m2, m3));
    const float sc0 = __builtin_amdgcn_exp2f(m - M);
    const float sc1 = __builtin_amdgcn_exp2f(m1 - M);
    const float sc2 = __builtin_amdgcn_exp2f(m2 - M);
    const float sc3 = __builtin_amdgcn_exp2f(m3 - M);
    const float L = lsum * sc0 + l1 * sc1 + l2 * sc2 + l3 * sc3;
    const float rl = __builtin_amdgcn_rcpf(L);
    const float a0 = sc0 * rl, a1 = sc1 * rl, a2 = sc2 * rl, a3 = sc3 * rl;
    const int b = bh >> 4, h = bh & 15;
    u16* orow = AO + ((size_t)(b * 2048 + q)) * 1024 + h * 64;
#pragma unroll
    for (int r4 = 0; r4 < 4; ++r4) {
      const f32x4 pa1 = *(const f32x4*)&o_lds[0][r4][l][0];
      const f32x4 pb1 = *(const f32x4*)&o_lds[0][r4 + 4][l][0];
      const f32x4 pa2 = *(const f32x4*)&o_lds[1][r4][l][0];
      const f32x4 pb2 = *(const f32x4*)&o_lds[1][r4 + 4][l][0];
      const f32x4 pa3 = *(const f32x4*)&o_lds[2][r4][l][0];
      const f32x4 pb3 = *(const f32x4*)&o_lds[2][r4 + 4][l][0];
      float e[4], f[4];
#pragma unroll
      for (int t = 0; t < 4; ++t) {
        e[t] = oA[4 * r4 + t] * a0 + pa1[t] * a1 + pa2[t] * a2 + pa3[t] * a3;
        f[t] = oB[4 * r4 + t] * a0 + pb1[t] * a1 + pb2[t] * a2 + pb3[t] * a3;
      }
      u32 w0, w1, w2, w3;
      asm("v_cvt_pk_bf16_f32 %0, %1, %2" : "=v"(w0) : "v"(e[0]), "v"(e[1]));
      asm("v_cvt_pk_bf16_f32 %0, %1, %2" : "=v"(w1) : "v"(e[2]), "v"(e[3]));
      asm("v_cvt_pk_bf16_f32 %0, %1, %2" : "=v"(w2) : "v"(f[0]), "v"(f[1]));
      asm("v_cvt_pk_bf16_f32 %0, %1, %2" : "=v"(w3) : "v"(f[2]), "v"(f[3]));
      uint2 uA; uA.x = w0; uA.y = w1;
      uint2 uB; uB.x = w2; uB.y = w3;
      *(uint2*)&orow[8 * r4 + 4 * hi] = uA;        // d = 8*r4+4hi .. +3
      *(uint2*)&orow[32 + 8 * r4 + 4 * hi] = uB;   // d+32
    }
  }
}

// ---------------- launch ----------------

extern "C" void kernel_launch(void* const* d_in, const int* in_sizes, int n_in,
                              void* d_out, int out_size, void* d_ws, size_t ws_size,
                              hipStream_t stream) {
  const float* hs = (const float*)d_in[0];
  const float* w1 = (const float*)d_in[1];
  const float* b1 = (const float*)d_in[2];
  const float* w2 = (const float*)d_in[3];
  const float* b2 = (const float*)d_in[4];
  float* out = (float*)d_out;

  char* ws = (char*)d_ws;
  u16* Xb  = (u16*)(ws);                    // [4096][1024] bf16   (8 MB)
  u16* W1t = (u16*)(ws + (8ull  << 20));    // [3072][1024] bf16   (6 MB)
  u16* W2t = (u16*)(ws + (14ull << 20));    // [1024][1024] bf16   (2 MB)
  u16* Qb  = (u16*)(ws + (16ull << 20));    // [B,H,S,D] bf16      (8 MB)
  u16* Kb  = (u16*)(ws + (24ull << 20));    // [B,H,S,D] bf16      (8 MB)
  u16* Vtb = (u16*)(ws + (32ull << 20));    // [B,H,D,S] bf16      (8 MB)
  u16* AO  = (u16*)(ws + (40ull << 20));    // [4096][1024] bf16   (8 MB)

  cvt_f32_bf16<<<dim3(2048), dim3(256), 0, stream>>>(hs, Xb, 4096 * 1024 / 4);
  transpose_bf16<<<dim3(96, 32), dim3(32, 8), 0, stream>>>(w1, W1t, 1024, 3072);
  transpose_bf16<<<dim3(32, 32), dim3(32, 8), 0, stream>>>(w2, W2t, 1024, 1024);
  gemm_bt<0><<<dim3(24, 32), dim3(256), 0, stream>>>(Xb, W1t, b1, Qb, Kb, Vtb, nullptr);
  attn_fwd5<<<dim3(2048), dim3(256), 0, stream>>>(Qb, Kb, Vtb, AO);
  gemm_bt<1><<<dim3(8, 32), dim3(256), 0, stream>>>(AO, W2t, b2, nullptr, nullptr, nullptr, out);
}

// Round 6
// 125.138 us; speedup vs baseline: 1.2158x; 1.2158x over previous
//
#include <hip/hip_runtime.h>
#include <stdint.h>

// Problem constants: B=2, S=2048, E=1024, H=16, D=64, M = B*S = 4096
#define LOG2E 1.4426950408889634f
#define QSCALE (0.125f * LOG2E)   // fold 1/sqrt(64) and log2(e): softmax in exp2 domain

using u16 = unsigned short;
using u32 = unsigned int;

typedef __attribute__((ext_vector_type(8))) short short8;
typedef __attribute__((ext_vector_type(4))) float f32x4;
typedef __attribute__((ext_vector_type(16))) float f32x16;

__device__ __forceinline__ u16 f32_bf16(float f) {
  union { float f; u32 u; } v; v.f = f;
  u32 u = v.u;
  u += 0x7FFF + ((u >> 16) & 1);   // RNE
  return (u16)(u >> 16);
}

__device__ __forceinline__ float max3f(float a, float b, float c) {
  return fmaxf(fmaxf(a, b), c);    // clang fuses to v_max3_f32
}

__device__ __forceinline__ void gload_lds16(const void* g, void* l) {
  __builtin_amdgcn_global_load_lds(
      (const __attribute__((address_space(1))) u32*)(uintptr_t)g,
      (__attribute__((address_space(3))) u32*)(u32)(uintptr_t)l, 16, 0, 0);
}

// ---------------- pre-passes ----------------

__global__ __launch_bounds__(256) void cvt_f32_bf16(const float* __restrict__ in,
                                                    u16* __restrict__ out, int n4) {
  for (int i = blockIdx.x * blockDim.x + threadIdx.x; i < n4;
       i += gridDim.x * blockDim.x) {
    float4 v = ((const float4*)in)[i];
    union { u16 h[4]; uint2 u; } o;
    o.h[0] = f32_bf16(v.x); o.h[1] = f32_bf16(v.y);
    o.h[2] = f32_bf16(v.z); o.h[3] = f32_bf16(v.w);
    ((uint2*)out)[i] = o.u;
  }
}

// out[n][k] = bf16(in[k][n]);  in is [K][N] fp32 row-major
__global__ __launch_bounds__(256) void transpose_bf16(const float* __restrict__ in,
                                                      u16* __restrict__ out,
                                                      int K, int N) {
  __shared__ float t[32][33];
  const int n0 = blockIdx.x * 32, k0 = blockIdx.y * 32;
  const int tx = threadIdx.x, ty = threadIdx.y;
#pragma unroll
  for (int j = 0; j < 32; j += 8)
    t[ty + j][tx] = in[(size_t)(k0 + ty + j) * N + n0 + tx];
  __syncthreads();
#pragma unroll
  for (int j = 0; j < 32; j += 8)
    out[(size_t)(n0 + ty + j) * K + k0 + tx] = f32_bf16(t[tx][ty + j]);
}

// ---------------- GEMM: C = A[M,K] * Bt[N,K]^T + bias ----------------
// 128x128 tile, 4 waves (2x2), BK=32, global_load_lds staging (m97 structure).
// MODE 0: QKV epilogue -> scatter to Q[B,H,S,D]*QSCALE, K[B,H,S,D], Vt[B,H,D,S] (bf16)
// MODE 1: fp32 out + bias to fout[M,1024]
template <int MODE>
__global__ __launch_bounds__(256) void gemm_bt(
    const u16* __restrict__ A, const u16* __restrict__ Bt,
    const float* __restrict__ bias,
    u16* __restrict__ qb, u16* __restrict__ kb, u16* __restrict__ vtb,
    float* __restrict__ fout) {
  __shared__ u16 lA[128 * 32];
  __shared__ u16 lB[128 * 32];
  const int tid = threadIdx.x;
  const int w = tid >> 6, l = tid & 63;
  const int bm = blockIdx.y, bn = blockIdx.x;
  const size_t m0 = (size_t)bm * 128, n0 = (size_t)bn * 128;
  const int wr = w >> 1, wc = w & 1;

  f32x4 acc[4][4] = {};

  const int arow = w * 16 + (l >> 2);
  const int acol = (l & 3) * 8;
  const u16* gA = A + (m0 + arow) * 1024 + acol;
  const u16* gB = Bt + (n0 + arow) * 1024 + acol;
  u16* lAw = lA + w * 512;  // HW adds lane*16B
  u16* lBw = lB + w * 512;

  for (int k0 = 0; k0 < 1024; k0 += 32) {
    gload_lds16(gA + k0, lAw);
    gload_lds16(gA + k0 + 64 * 1024, lAw + 2048);
    gload_lds16(gB + k0, lBw);
    gload_lds16(gB + k0 + 64 * 1024, lBw + 2048);
    __syncthreads();
    short8 af[4], bf[4];
#pragma unroll
    for (int m = 0; m < 4; ++m)
      af[m] = *(const short8*)&lA[(wr * 64 + m * 16 + (l & 15)) * 32 + (l >> 4) * 8];
#pragma unroll
    for (int n = 0; n < 4; ++n)
      bf[n] = *(const short8*)&lB[(wc * 64 + n * 16 + (l & 15)) * 32 + (l >> 4) * 8];
#pragma unroll
    for (int m = 0; m < 4; ++m)
#pragma unroll
      for (int n = 0; n < 4; ++n)
        acc[m][n] = __builtin_amdgcn_mfma_f32_16x16x32_bf16(af[m], bf[n], acc[m][n], 0, 0, 0);
    __syncthreads();
  }

  if (MODE == 0) {
#pragma unroll
    for (int m = 0; m < 4; ++m) {
      const int row = (int)m0 + wr * 64 + m * 16 + ((l >> 4) << 2);
      const int b = row >> 11, s = row & 2047;
#pragma unroll
      for (int n = 0; n < 4; ++n) {
        const int col = (int)n0 + wc * 64 + n * 16 + (l & 15);
        const int part = col >> 10;
        const int h = (col & 1023) >> 6, d = col & 63;
        const float bv = bias[col];
        const size_t bh = (size_t)(b * 16 + h);
#pragma unroll
        for (int r = 0; r < 4; ++r) {
          const float v = acc[m][n][r] + bv;
          const int ss = s + r;
          if (part == 0)
            qb[(bh * 2048 + ss) * 64 + d] = f32_bf16(v * QSCALE);
          else if (part == 1)
            kb[(bh * 2048 + ss) * 64 + d] = f32_bf16(v);
          else
            vtb[(bh * 64 + d) * 2048 + ss] = f32_bf16(v);  // V transposed
        }
      }
    }
  } else {
#pragma unroll
    for (int m = 0; m < 4; ++m) {
      const size_t row = m0 + wr * 64 + m * 16 + ((l >> 4) << 2);
#pragma unroll
      for (int n = 0; n < 4; ++n) {
        const size_t col = n0 + wc * 64 + n * 16 + (l & 15);
        const float bv = bias[col];
#pragma unroll
        for (int r = 0; r < 4; ++r)
          fout[(row + r) * 1024 + col] = acc[m][n][r] + bv;
      }
    }
  }
}

// ---------------- causal flash attention: LDS-staged K/V, 4 waves share ----------------
// 512 blocks x 256 threads; block = (bh, 128 q-rows); wave w owns q rows [qb*128+32w, +32).
// kv loop over 64-kv chunks; K[64s][64d] and Vt[64d][64s] staged in LDS (double-buffered)
// via global_load_lds w16 with pre-swizzled source (slot ^= row&7); all 4 waves share.
// Swapped-operand 32x32x16 MFMAs, in-register online softmax (pack+permlane P path).
__global__ __launch_bounds__(256) void attn_fwd6(const u16* __restrict__ Qb,
                                                 const u16* __restrict__ Kb,
                                                 const u16* __restrict__ Vt,
                                                 u16* __restrict__ AO) {
  __shared__ u16 lK[2][4096];   // [buf][row*64 + swizzled slot*8 .. ]  row-major 128B rows
  __shared__ u16 lV[2][4096];
  const int tid = threadIdx.x;
  const int l = tid & 63, w = tid >> 6;
  const int lq = l & 31, hi = l >> 5;
  const int bid = blockIdx.x;
  // XCD k serves bh {4k..4k+3}; heaviest q-blocks dispatch first (LPT).
  const int xcd = bid & 7, idx = bid >> 3;
  const int bh = xcd * 4 + (idx & 3);
  const int qb = 15 - (idx >> 2);        // q-block 0..15 (128 rows each)
  const int qw = qb * 128 + w * 32;      // wave's q base
  const int q = qw + lq;
  const int cdiag = 2 * qb + (w >> 1);   // wave's diagonal chunk
  const int NT = 2 * qb + 2;             // chunks this block processes

  const u16* Qh = Qb + (size_t)bh * 131072;
  const u16* Kh = Kb + (size_t)bh * 131072;
  const u16* Vh = Vt + (size_t)bh * 131072;

  // Q B-fragments (col=q=lane&31, k=d), 4 mfmas cover D=64
  short8 qf[4];
#pragma unroll
  for (int kk = 0; kk < 4; ++kk)
    qf[kk] = *(const short8*)&Qh[(size_t)q * 64 + kk * 16 + hi * 8];

  f32x16 oA = {}, oB = {};               // O^T cols: d 0..31 / 32..63
  float m = -3.0e38f, lsum = 0.f;

  // staging geometry: lane covers row8 = l>>3, slot = l&7; source slot pre-swizzled
  const int srow = l >> 3, sslot = l & 7;
  const int swz = ((sslot ^ srow) << 3);           // elements
  const u16* kbase = Kh + (16 * w + srow) * 64 + swz;
  const u16* vbase = Vh + (size_t)(16 * w + srow) * 2048 + swz;
  char* lKw0 = (char*)&lK[0][0] + 2 * w * 1024;    // wave-uniform dests
  char* lVw0 = (char*)&lV[0][0] + 2 * w * 1024;

  auto stage = [&](int buf, int c) {
    const u16* ks = kbase + c * 4096;
    const u16* vs = vbase + c * 64;
    char* kd = lKw0 + buf * 8192;
    char* vd = lVw0 + buf * 8192;
    gload_lds16(ks, kd);
    gload_lds16(ks + 512, kd + 1024);        // +8 K rows
    gload_lds16(vs, vd);
    gload_lds16(vs + 16384, vd + 1024);      // +8 V^T rows (d)
  };

  const int swsl = (lq & 7);                 // read-side swizzle key

  auto pack16 = [&](const f32x16& st, short8& lo, short8& hi8) {
    u32 pk[8];
#pragma unroll
    for (int t2 = 0; t2 < 8; ++t2)
      asm("v_cvt_pk_bf16_f32 %0, %1, %2" : "=v"(pk[t2]) : "v"(st[2 * t2]), "v"(st[2 * t2 + 1]));
    u32 a0 = pk[0], a1 = pk[2]; asm("v_permlane32_swap_b32 %0, %1" : "+v"(a0), "+v"(a1));
    u32 a2 = pk[1], a3 = pk[3]; asm("v_permlane32_swap_b32 %0, %1" : "+v"(a2), "+v"(a3));
    u32 c0 = pk[4], c1 = pk[6]; asm("v_permlane32_swap_b32 %0, %1" : "+v"(c0), "+v"(c1));
    u32 c2 = pk[5], c3 = pk[7]; asm("v_permlane32_swap_b32 %0, %1" : "+v"(c2), "+v"(c3));
    union { u32 u[4]; short8 s; } f0, f1;
    f0.u[0] = a0; f0.u[1] = a2; f0.u[2] = a1; f0.u[3] = a3;   // kv 0..15
    f1.u[0] = c0; f1.u[1] = c2; f1.u[2] = c1; f1.u[3] = c3;   // kv 16..31
    lo = f0.s; hi8 = f1.s;
  };

  // full 64-kv chunk; mask2 => causal-mask tile1 (odd-wave diagonal)
  auto body64 = [&](int buf, bool mask2) {
    const char* kb = (const char*)&lK[buf][0] + lq * 128;
    const char* vb = (const char*)&lV[buf][0] + lq * 128;
    short8 kf0[4], kf1[4];
#pragma unroll
    for (int kk = 0; kk < 4; ++kk) {
      const int sl = ((2 * kk + hi) ^ swsl) << 4;
      kf0[kk] = *(const short8*)(kb + sl);
      kf1[kk] = *(const short8*)(kb + 4096 + sl);
    }
    f32x16 st0 = {}, st1 = {};
    __builtin_amdgcn_s_setprio(1);
#pragma unroll
    for (int kk = 0; kk < 4; ++kk)
      st0 = __builtin_amdgcn_mfma_f32_32x32x16_bf16(kf0[kk], qf[kk], st0, 0, 0, 0);
#pragma unroll
    for (int kk = 0; kk < 4; ++kk)
      st1 = __builtin_amdgcn_mfma_f32_32x32x16_bf16(kf1[kk], qf[kk], st1, 0, 0, 0);
    __builtin_amdgcn_s_setprio(0);

    short8 vfA[4], vfB[4];
#pragma unroll
    for (int ks = 0; ks < 4; ++ks) {
      const int sl = ((2 * ks + hi) ^ swsl) << 4;
      vfA[ks] = *(const short8*)(vb + sl);
      vfB[ks] = *(const short8*)(vb + 4096 + sl);
    }

    if (mask2) {
      const int qm = lq - hi * 4;
#pragma unroll
      for (int r = 0; r < 16; ++r) {
        const int t = (r & 3) + 8 * (r >> 2);
        if (t > qm) st1[r] = -3.0e38f;
      }
    }

    // row max over 64 kv (max3 tree) + cross-half exchange
    float a0 = max3f(st0[0], st0[1], st0[2]);
    float a1 = max3f(st0[3], st0[4], st0[5]);
    float a2 = max3f(st0[6], st0[7], st0[8]);
    float a3 = max3f(st0[9], st0[10], st0[11]);
    float a4 = max3f(st0[12], st0[13], st0[14]);
    float a5 = max3f(st0[15], st1[0], st1[1]);
    float a6 = max3f(st1[2], st1[3], st1[4]);
    float a7 = max3f(st1[5], st1[6], st1[7]);
    float a8 = max3f(st1[8], st1[9], st1[10]);
    float a9 = max3f(st1[11], st1[12], st1[13]);
    float a10 = fmaxf(st1[14], st1[15]);
    float b0 = max3f(a0, a1, a2);
    float b1 = max3f(a3, a4, a5);
    float b2 = max3f(a6, a7, a8);
    float b3 = max3f(a9, a10, b0);
    float pm = max3f(b1, b2, b3);
    pm = fmaxf(pm, __shfl_xor(pm, 32));

    if (!__all(pm <= m + 8.0f)) {        // defer-max (T13)
      const float mn = fmaxf(m, pm);
      const float alpha = __builtin_amdgcn_exp2f(m - mn);
      lsum *= alpha;
#pragma unroll
      for (int r = 0; r < 16; ++r) { oA[r] *= alpha; oB[r] *= alpha; }
      m = mn;
    }

#pragma unroll
    for (int r = 0; r < 16; ++r) st0[r] = __builtin_amdgcn_exp2f(st0[r] - m);
#pragma unroll
    for (int r = 0; r < 16; ++r) st1[r] = __builtin_amdgcn_exp2f(st1[r] - m);

    float s0 = (st0[0] + st0[1]) + (st0[2] + st0[3]);
    float s1 = (st0[4] + st0[5]) + (st0[6] + st0[7]);
    float s2 = (st0[8] + st0[9]) + (st0[10] + st0[11]);
    float s3 = (st0[12] + st0[13]) + (st0[14] + st0[15]);
    float s4 = (st1[0] + st1[1]) + (st1[2] + st1[3]);
    float s5 = (st1[4] + st1[5]) + (st1[6] + st1[7]);
    float s6 = (st1[8] + st1[9]) + (st1[10] + st1[11]);
    float s7 = (st1[12] + st1[13]) + (st1[14] + st1[15]);
    float rs = ((s0 + s1) + (s2 + s3)) + ((s4 + s5) + (s6 + s7));
    rs += __shfl_xor(rs, 32);
    lsum += rs;

    short8 pf0, pf1, pf2, pf3;
    pack16(st0, pf0, pf1);
    pack16(st1, pf2, pf3);

    __builtin_amdgcn_s_setprio(1);
    oA = __builtin_amdgcn_mfma_f32_32x32x16_bf16(vfA[0], pf0, oA, 0, 0, 0);
    oA = __builtin_amdgcn_mfma_f32_32x32x16_bf16(vfA[1], pf1, oA, 0, 0, 0);
    oA = __builtin_amdgcn_mfma_f32_32x32x16_bf16(vfA[2], pf2, oA, 0, 0, 0);
    oA = __builtin_amdgcn_mfma_f32_32x32x16_bf16(vfA[3], pf3, oA, 0, 0, 0);
    oB = __builtin_amdgcn_mfma_f32_32x32x16_bf16(vfB[0], pf0, oB, 0, 0, 0);
    oB = __builtin_amdgcn_mfma_f32_32x32x16_bf16(vfB[1], pf1, oB, 0, 0, 0);
    oB = __builtin_amdgcn_mfma_f32_32x32x16_bf16(vfB[2], pf2, oB, 0, 0, 0);
    oB = __builtin_amdgcn_mfma_f32_32x32x16_bf16(vfB[3], pf3, oB, 0, 0, 0);
    __builtin_amdgcn_s_setprio(0);
  };

  // diagonal chunk for even waves: tile0 only, causal-masked
  auto body32m = [&](int buf) {
    const char* kb = (const char*)&lK[buf][0] + lq * 128;
    const char* vb = (const char*)&lV[buf][0] + lq * 128;
    short8 kf0[4];
#pragma unroll
    for (int kk = 0; kk < 4; ++kk)
      kf0[kk] = *(const short8*)(kb + (((2 * kk + hi) ^ swsl) << 4));
    f32x16 st0 = {};
    __builtin_amdgcn_s_setprio(1);
#pragma unroll
    for (int kk = 0; kk < 4; ++kk)
      st0 = __builtin_amdgcn_mfma_f32_32x32x16_bf16(kf0[kk], qf[kk], st0, 0, 0, 0);
    __builtin_amdgcn_s_setprio(0);

    short8 vfA[2], vfB[2];
#pragma unroll
    for (int ks = 0; ks < 2; ++ks) {
      const int sl = ((2 * ks + hi) ^ swsl) << 4;
      vfA[ks] = *(const short8*)(vb + sl);
      vfB[ks] = *(const short8*)(vb + 4096 + sl);
    }

    const int qm = lq - hi * 4;
#pragma unroll
    for (int r = 0; r < 16; ++r) {
      const int t = (r & 3) + 8 * (r >> 2);
      if (t > qm) st0[r] = -3.0e38f;
    }
    float a0 = max3f(st0[0], st0[1], st0[2]);
    float a1 = max3f(st0[3], st0[4], st0[5]);
    float a2 = max3f(st0[6], st0[7], st0[8]);
    float a3 = max3f(st0[9], st0[10], st0[11]);
    float a4 = max3f(st0[12], st0[13], st0[14]);
    float b0 = max3f(a0, a1, a2);
    float b1 = max3f(a3, a4, st0[15]);
    float pm = fmaxf(b0, b1);
    pm = fmaxf(pm, __shfl_xor(pm, 32));
    if (!__all(pm <= m + 8.0f)) {
      const float mn = fmaxf(m, pm);
      const float alpha = __builtin_amdgcn_exp2f(m - mn);
      lsum *= alpha;
#pragma unroll
      for (int r = 0; r < 16; ++r) { oA[r] *= alpha; oB[r] *= alpha; }
      m = mn;
    }
#pragma unroll
    for (int r = 0; r < 16; ++r) st0[r] = __builtin_amdgcn_exp2f(st0[r] - m);
    float s0 = (st0[0] + st0[1]) + (st0[2] + st0[3]);
    float s1 = (st0[4] + st0[5]) + (st0[6] + st0[7]);
    float s2 = (st0[8] + st0[9]) + (st0[10] + st0[11]);
    float s3 = (st0[12] + st0[13]) + (st0[14] + st0[15]);
    float rs = (s0 + s1) + (s2 + s3);
    rs += __shfl_xor(rs, 32);
    lsum += rs;

    short8 pf0, pf1;
    pack16(st0, pf0, pf1);
    __builtin_amdgcn_s_setprio(1);
    oA = __builtin_amdgcn_mfma_f32_32x32x16_bf16(vfA[0], pf0, oA, 0, 0, 0);
    oA = __builtin_amdgcn_mfma_f32_32x32x16_bf16(vfA[1], pf1, oA, 0, 0, 0);
    oB = __builtin_amdgcn_mfma_f32_32x32x16_bf16(vfB[0], pf0, oB, 0, 0, 0);
    oB = __builtin_amdgcn_mfma_f32_32x32x16_bf16(vfB[1], pf1, oB, 0, 0, 0);
    __builtin_amdgcn_s_setprio(0);
  };

  // 2-phase pipeline: stage(next) issued before compute(current); barrier drains both.
  stage(0, 0);
  __syncthreads();
  int cur = 0;
  for (int c = 0; c < NT; ++c) {
    if (c + 1 < NT) stage(cur ^ 1, c + 1);
    if (c < cdiag) body64(cur, false);
    else if (c == cdiag) { if (w & 1) body64(cur, true); else body32m(cur); }
    // waves past their causal range only stage + barrier
    __syncthreads();
    cur ^= 1;
  }

  // epilogue: O[q][d] = O^T/lsum, merged heads AO[b*2048+q][h*64+d]
  const float rl = __builtin_amdgcn_rcpf(lsum);
  const int b = bh >> 4, h = bh & 15;
  u16* orow = AO + ((size_t)(b * 2048 + q)) * 1024 + h * 64;
#pragma unroll
  for (int g = 0; g < 4; ++g) {
    float e0 = oA[4 * g] * rl, e1 = oA[4 * g + 1] * rl;
    float e2 = oA[4 * g + 2] * rl, e3 = oA[4 * g + 3] * rl;
    float f0 = oB[4 * g] * rl, f1 = oB[4 * g + 1] * rl;
    float f2 = oB[4 * g + 2] * rl, f3 = oB[4 * g + 3] * rl;
    u32 w0, w1, w2, w3;
    asm("v_cvt_pk_bf16_f32 %0, %1, %2" : "=v"(w0) : "v"(e0), "v"(e1));
    asm("v_cvt_pk_bf16_f32 %0, %1, %2" : "=v"(w1) : "v"(e2), "v"(e3));
    asm("v_cvt_pk_bf16_f32 %0, %1, %2" : "=v"(w2) : "v"(f0), "v"(f1));
    asm("v_cvt_pk_bf16_f32 %0, %1, %2" : "=v"(w3) : "v"(f2), "v"(f3));
    uint2 uA; uA.x = w0; uA.y = w1;
    uint2 uB; uB.x = w2; uB.y = w3;
    *(uint2*)&orow[8 * g + 4 * hi] = uA;        // d = 8g+4hi .. +3
    *(uint2*)&orow[32 + 8 * g + 4 * hi] = uB;   // d+32
  }
}

// ---------------- launch ----------------

extern "C" void kernel_launch(void* const* d_in, const int* in_sizes, int n_in,
                              void* d_out, int out_size, void* d_ws, size_t ws_size,
                              hipStream_t stream) {
  const float* hs = (const float*)d_in[0];
  const float* w1 = (const float*)d_in[1];
  const float* b1 = (const float*)d_in[2];
  const float* w2 = (const float*)d_in[3];
  const float* b2 = (const float*)d_in[4];
  float* out = (float*)d_out;

  char* ws = (char*)d_ws;
  u16* Xb  = (u16*)(ws);                    // [4096][1024] bf16   (8 MB)
  u16* W1t = (u16*)(ws + (8ull  << 20));    // [3072][1024] bf16   (6 MB)
  u16* W2t = (u16*)(ws + (14ull << 20));    // [1024][1024] bf16   (2 MB)
  u16* Qb  = (u16*)(ws + (16ull << 20));    // [B,H,S,D] bf16      (8 MB)
  u16* Kb  = (u16*)(ws + (24ull << 20));    // [B,H,S,D] bf16      (8 MB)
  u16* Vtb = (u16*)(ws + (32ull << 20));    // [B,H,D,S] bf16      (8 MB)
  u16* AO  = (u16*)(ws + (40ull << 20));    // [4096][1024] bf16   (8 MB)

  cvt_f32_bf16<<<dim3(2048), dim3(256), 0, stream>>>(hs, Xb, 4096 * 1024 / 4);
  transpose_bf16<<<dim3(96, 32), dim3(32, 8), 0, stream>>>(w1, W1t, 1024, 3072);
  transpose_bf16<<<dim3(32, 32), dim3(32, 8), 0, stream>>>(w2, W2t, 1024, 1024);
  gemm_bt<0><<<dim3(24, 32), dim3(256), 0, stream>>>(Xb, W1t, b1, Qb, Kb, Vtb, nullptr);
  attn_fwd6<<<dim3(512), dim3(256), 0, stream>>>(Qb, Kb, Vtb, AO);
  gemm_bt<1><<<dim3(8, 32), dim3(256), 0, stream>>>(AO, W2t, b2, nullptr, nullptr, nullptr, out);
}